// Round 1
// baseline (39.807 us; speedup 1.0000x reference)
//
#include <hip/hip_runtime.h>
#include <math.h>

// Sizes fixed by the reference problem.
namespace {
constexpr int NB   = 256;   // molecules
constexpr int NA   = 64;    // atoms per molecule
constexpr int EMBD = 64;    // embedding dim
constexpr int NG   = 64;    // gaussians
constexpr int HIDD = 128;   // hidden dim (= EMBD + NG)
constexpr int OUTD = 512;   // output dim

__device__ __forceinline__ float gelu_exact(float x) {
    // jax.nn.gelu(approximate=False) = x * 0.5 * (1 + erf(x/sqrt(2)))
    return 0.5f * x * (1.0f + erff(x * 0.7071067811865475f));
}

__global__ __launch_bounds__(512, 1)
void mlip_fused(const int*   __restrict__ atomic_nums,   // [NB,NA]
                const float* __restrict__ coords,        // [NB,NA,3]
                const float* __restrict__ embed_table,   // [120,EMBD]
                const float* __restrict__ W1,            // [HIDD,HIDD] (in,out)
                const float* __restrict__ b1,            // [HIDD]
                const float* __restrict__ W2,            // [HIDD,HIDD]
                const float* __restrict__ b2,            // [HIDD]
                const float* __restrict__ Wo,            // [HIDD,OUTD]
                const float* __restrict__ bo,            // [OUTD]
                const float* __restrict__ centers,       // [NG]
                float*       __restrict__ out)           // [NB,OUTD]
{
    const int b   = blockIdx.x;
    const int tid = threadIdx.x;

    __shared__ float s_cx[NA], s_cy[NA], s_cz[NA];
    __shared__ int   s_z[NA];
    __shared__ float s_feat[NA][HIDD];     // 32 KB: [emb | avg_gauss]
    __shared__ float s_hd[NA * HIDD];      // 32 KB: dists [64][64], then h [64][128]
    __shared__ float s_mol[16][HIDD];      // 8 KB: per-ty partial atom sums
    __shared__ float s_molv[HIDD];         // final mol vector

    // ---- stage 0: coords + atomic numbers
    if (tid < NA) {
        const float* cp = coords + ((size_t)b * NA + tid) * 3;
        s_cx[tid] = cp[0];
        s_cy[tid] = cp[1];
        s_cz[tid] = cp[2];
        s_z[tid]  = atomic_nums[b * NA + tid];
    }
    __syncthreads();

    // ---- stage 1a: embedding gather -> s_feat[:, 0:64]
    {
        const int e4 = (tid & 15) * 4;
        #pragma unroll
        for (int it = 0; it < 2; ++it) {
            const int i = (tid >> 4) + it * 32;
            const int z = s_z[i];
            *(float4*)&s_feat[i][e4] =
                *(const float4*)(embed_table + (size_t)z * EMBD + e4);
        }
    }
    // ---- stage 1b: pairwise distances -> s_hd (as [NA][NA])
    #pragma unroll
    for (int it = 0; it < 8; ++it) {
        const int p = tid + it * 512;
        const int i = p >> 6, j = p & 63;
        const float dx = s_cx[i] - s_cx[j];
        const float dy = s_cy[i] - s_cy[j];
        const float dz = s_cz[i] - s_cz[j];
        const float sq = dx * dx + dy * dy + dz * dz;
        s_hd[p] = sq > 0.0f ? sqrtf(sq) : 0.0f;
    }
    __syncthreads();

    // ---- stage 2: gaussian smear, mean over j -> s_feat[:, 64:128]
    // exp(-0.5*((d-c)/0.5)^2) = exp(-2 (d-c)^2) = exp2(K2 * (d-c)^2)
    {
        const int   g  = tid & 63;        // wave-uniform i => LDS broadcast reads
        const float c  = centers[g];
        const float K2 = -2.8853900817779268f;  // -2 * log2(e)
        #pragma unroll 2
        for (int it = 0; it < 8; ++it) {
            const int i = (tid >> 6) + it * 8;
            const float* drow = &s_hd[i * NA];
            float acc = 0.0f;
            #pragma unroll
            for (int j4 = 0; j4 < NA; j4 += 4) {
                const float4 d4 = *(const float4*)(drow + j4);
                const float t0 = d4.x - c;
                const float t1 = d4.y - c;
                const float t2 = d4.z - c;
                const float t3 = d4.w - c;
                acc += __builtin_amdgcn_exp2f(K2 * t0 * t0);
                acc += __builtin_amdgcn_exp2f(K2 * t1 * t1);
                acc += __builtin_amdgcn_exp2f(K2 * t2 * t2);
                acc += __builtin_amdgcn_exp2f(K2 * t3 * t3);
            }
            s_feat[i][EMBD + g] = acc * (1.0f / 64.0f);
        }
    }
    __syncthreads();

    const int tx = tid & 31;
    const int ty = tid >> 5;      // [0,16)
    const int j0 = tx * 4;
    const int i0 = ty * 4;

    // ---- stage 3: h = gelu(feat @ W1 + b1) -> s_hd as [NA][HIDD]
    {
        float4 acc[4];
        #pragma unroll
        for (int r = 0; r < 4; ++r) acc[r] = make_float4(0.f, 0.f, 0.f, 0.f);

        #pragma unroll 2
        for (int kk = 0; kk < HIDD; kk += 4) {
            float4 a[4];
            #pragma unroll
            for (int r = 0; r < 4; ++r)
                a[r] = *(const float4*)&s_feat[i0 + r][kk];
            const float4 w0 = *(const float4*)(W1 + (size_t)(kk + 0) * HIDD + j0);
            const float4 w1 = *(const float4*)(W1 + (size_t)(kk + 1) * HIDD + j0);
            const float4 w2 = *(const float4*)(W1 + (size_t)(kk + 2) * HIDD + j0);
            const float4 w3 = *(const float4*)(W1 + (size_t)(kk + 3) * HIDD + j0);
            #pragma unroll
            for (int r = 0; r < 4; ++r) {
                acc[r].x += a[r].x * w0.x; acc[r].y += a[r].x * w0.y;
                acc[r].z += a[r].x * w0.z; acc[r].w += a[r].x * w0.w;
                acc[r].x += a[r].y * w1.x; acc[r].y += a[r].y * w1.y;
                acc[r].z += a[r].y * w1.z; acc[r].w += a[r].y * w1.w;
                acc[r].x += a[r].z * w2.x; acc[r].y += a[r].z * w2.y;
                acc[r].z += a[r].z * w2.z; acc[r].w += a[r].z * w2.w;
                acc[r].x += a[r].w * w3.x; acc[r].y += a[r].w * w3.y;
                acc[r].z += a[r].w * w3.z; acc[r].w += a[r].w * w3.w;
            }
        }
        const float4 bb = *(const float4*)(b1 + j0);
        #pragma unroll
        for (int r = 0; r < 4; ++r) {
            float4 hv;
            hv.x = gelu_exact(acc[r].x + bb.x);
            hv.y = gelu_exact(acc[r].y + bb.y);
            hv.z = gelu_exact(acc[r].z + bb.z);
            hv.w = gelu_exact(acc[r].w + bb.w);
            *(float4*)&s_hd[(i0 + r) * HIDD + j0] = hv;
        }
    }
    __syncthreads();

    // ---- stage 4: h2 = h @ W2 (+b2 later); partial sum over this thread's rows
    {
        float4 acc[4];
        #pragma unroll
        for (int r = 0; r < 4; ++r) acc[r] = make_float4(0.f, 0.f, 0.f, 0.f);

        #pragma unroll 2
        for (int kk = 0; kk < HIDD; kk += 4) {
            float4 a[4];
            #pragma unroll
            for (int r = 0; r < 4; ++r)
                a[r] = *(const float4*)&s_hd[(i0 + r) * HIDD + kk];
            const float4 w0 = *(const float4*)(W2 + (size_t)(kk + 0) * HIDD + j0);
            const float4 w1 = *(const float4*)(W2 + (size_t)(kk + 1) * HIDD + j0);
            const float4 w2 = *(const float4*)(W2 + (size_t)(kk + 2) * HIDD + j0);
            const float4 w3 = *(const float4*)(W2 + (size_t)(kk + 3) * HIDD + j0);
            #pragma unroll
            for (int r = 0; r < 4; ++r) {
                acc[r].x += a[r].x * w0.x; acc[r].y += a[r].x * w0.y;
                acc[r].z += a[r].x * w0.z; acc[r].w += a[r].x * w0.w;
                acc[r].x += a[r].y * w1.x; acc[r].y += a[r].y * w1.y;
                acc[r].z += a[r].y * w1.z; acc[r].w += a[r].y * w1.w;
                acc[r].x += a[r].z * w2.x; acc[r].y += a[r].z * w2.y;
                acc[r].z += a[r].z * w2.z; acc[r].w += a[r].z * w2.w;
                acc[r].x += a[r].w * w3.x; acc[r].y += a[r].w * w3.y;
                acc[r].z += a[r].w * w3.z; acc[r].w += a[r].w * w3.w;
            }
        }
        float4 cs;
        cs.x = acc[0].x + acc[1].x + acc[2].x + acc[3].x;
        cs.y = acc[0].y + acc[1].y + acc[2].y + acc[3].y;
        cs.z = acc[0].z + acc[1].z + acc[2].z + acc[3].z;
        cs.w = acc[0].w + acc[1].w + acc[2].w + acc[3].w;
        *(float4*)&s_mol[ty][j0] = cs;
    }
    __syncthreads();

    // ---- stage 5: reduce 16 partials -> mol = mean_atoms(h2) + b2
    if (tid < HIDD) {
        float m = 0.0f;
        #pragma unroll
        for (int t = 0; t < 16; ++t) m += s_mol[t][tid];
        s_molv[tid] = m * (1.0f / 64.0f) + b2[tid];
    }
    __syncthreads();

    // ---- stage 6: out[b] = mol @ Wo + bo  (one output column per thread)
    {
        float a0 = bo[tid];
        #pragma unroll 4
        for (int k4 = 0; k4 < HIDD; k4 += 4) {
            const float4 m4 = *(const float4*)&s_molv[k4];
            a0 += m4.x * Wo[(size_t)(k4 + 0) * OUTD + tid];
            a0 += m4.y * Wo[(size_t)(k4 + 1) * OUTD + tid];
            a0 += m4.z * Wo[(size_t)(k4 + 2) * OUTD + tid];
            a0 += m4.w * Wo[(size_t)(k4 + 3) * OUTD + tid];
        }
        out[(size_t)b * OUTD + tid] = a0;
    }
}
} // namespace

extern "C" void kernel_launch(void* const* d_in, const int* in_sizes, int n_in,
                              void* d_out, int out_size, void* d_ws, size_t ws_size,
                              hipStream_t stream) {
    const int*   atomic_nums = (const int*)  d_in[0];
    const float* coords      = (const float*)d_in[1];
    const float* embed_table = (const float*)d_in[2];
    const float* W1          = (const float*)d_in[3];
    const float* b1          = (const float*)d_in[4];
    const float* W2          = (const float*)d_in[5];
    const float* b2          = (const float*)d_in[6];
    const float* Wo          = (const float*)d_in[7];
    const float* bo          = (const float*)d_in[8];
    const float* centers     = (const float*)d_in[9];
    float*       out         = (float*)d_out;

    mlip_fused<<<NB, 512, 0, stream>>>(atomic_nums, coords, embed_table,
                                       W1, b1, W2, b2, Wo, bo, centers, out);
}

// Round 2
// 31.348 us; speedup vs baseline: 1.2698x; 1.2698x over previous
//
#include <hip/hip_runtime.h>
#include <math.h>

namespace {
constexpr int NB   = 256;
constexpr int NA   = 64;
constexpr int EMBD = 64;
constexpr int HIDD = 128;
constexpr int OUTD = 512;
constexpr int FP   = 132;   // padded row stride for feat/h tiles (row*528B = 33*16B: float4-aligned,
                            // and 4*row mod 32 spreads MFMA A-frag reads to ~2-way conflicts = free)

typedef __attribute__((ext_vector_type(8))) short bfrag8;   // 8 bf16 (4 VGPRs) — guide §3
typedef __attribute__((ext_vector_type(4))) float floatx4;  // MFMA accumulator

__device__ __forceinline__ float gelu_exact(float x) {
    // jax.nn.gelu(approximate=False)
    return 0.5f * x * (1.0f + erff(x * 0.7071067811865475f));
}

__device__ __forceinline__ unsigned short bf16_rne(float f) {
    unsigned u = __float_as_uint(f);
    u += 0x7fffu + ((u >> 16) & 1u);
    return (unsigned short)(u >> 16);
}

// split 8 f32 into hi/lo bf16 fragments (3-term product keeps ~fp32 accuracy)
__device__ __forceinline__ void split8(const float* v, bfrag8& hi, bfrag8& lo) {
#pragma unroll
    for (int i = 0; i < 8; ++i) {
        const float f = v[i];
        const unsigned short h = bf16_rne(f);
        hi[i] = (short)h;
        lo[i] = (short)bf16_rne(f - __uint_as_float((unsigned)h << 16));
    }
}

__global__ __launch_bounds__(1024, 1)
void mlip_fused(const int*   __restrict__ atomic_nums,
                const float* __restrict__ coords,
                const float* __restrict__ embed_table,
                const float* __restrict__ W1, const float* __restrict__ b1,
                const float* __restrict__ W2, const float* __restrict__ b2,
                const float* __restrict__ Wo, const float* __restrict__ bo,
                const float* __restrict__ centers,
                float*       __restrict__ out)
{
    const int b    = blockIdx.x;
    const int tid  = threadIdx.x;
    const int lane = tid & 63;
    const int wid  = tid >> 6;          // 16 waves

    __shared__ float s_cx[NA], s_cy[NA], s_cz[NA];
    __shared__ int   s_z[NA];
    __shared__ float s_dist[NA * NA];   // 16 KB; reused as stage-6 reduction buffer
    __shared__ float s_feat[NA][FP];    // 33 KB: [emb | avg_gauss]
    __shared__ float s_h[NA][FP];       // 33 KB: GEMM1 output
    __shared__ float s_mol[4][HIDD];    // per-wm partial atom sums
    __shared__ float s_molv[HIDD];

    // ---- stage 0: coords + atomic numbers
    if (tid < NA) {
        const float* cp = coords + ((size_t)b * NA + tid) * 3;
        s_cx[tid] = cp[0]; s_cy[tid] = cp[1]; s_cz[tid] = cp[2];
        s_z[tid]  = atomic_nums[b * NA + tid];
    }
    __syncthreads();

    // ---- stage 1a: embedding gather -> s_feat[:, 0:64]  (1024 threads = 64 rows x 16 float4)
    {
        const int i = tid >> 4, e4 = (tid & 15) << 2;
        *(float4*)&s_feat[i][e4] =
            *(const float4*)(embed_table + (size_t)s_z[i] * EMBD + e4);
    }
    // ---- stage 1b: pairwise distances
#pragma unroll
    for (int it = 0; it < 4; ++it) {
        const int p = tid + (it << 10);
        const int i = p >> 6, j = p & 63;
        const float dx = s_cx[i] - s_cx[j];
        const float dy = s_cy[i] - s_cy[j];
        const float dz = s_cz[i] - s_cz[j];
        const float sq = dx * dx + dy * dy + dz * dz;
        s_dist[p] = sq > 0.0f ? sqrtf(sq) : 0.0f;
    }
    __syncthreads();

    // ---- stage 2: gaussian smear, mean over j -> s_feat[:, 64:128]
    // exp(-2(d-c)^2) = exp2(K2*d^2 - 2*K2*c*d + K2*c^2), 3 VALU + 1 trans per term
    {
        const float K2  = -2.8853900817779268f;   // -2*log2(e)
        const float c   = centers[lane];
        const float nu2 = -2.0f * K2 * c;
        const float vc  = K2 * c * c;
#pragma unroll
        for (int it = 0; it < 4; ++it) {
            const int i = wid + (it << 4);
            const float* drow = &s_dist[i << 6];  // wave-uniform row: LDS broadcast
            float acc = 0.0f;
#pragma unroll
            for (int j4 = 0; j4 < NA; j4 += 4) {
                const float4 d4 = *(const float4*)(drow + j4);
                acc += __builtin_amdgcn_exp2f(fmaf(d4.x, fmaf(K2, d4.x, nu2), vc));
                acc += __builtin_amdgcn_exp2f(fmaf(d4.y, fmaf(K2, d4.y, nu2), vc));
                acc += __builtin_amdgcn_exp2f(fmaf(d4.z, fmaf(K2, d4.z, nu2), vc));
                acc += __builtin_amdgcn_exp2f(fmaf(d4.w, fmaf(K2, d4.w, nu2), vc));
            }
            s_feat[i][EMBD + lane] = acc * (1.0f / 64.0f);
        }
    }
    __syncthreads();

    // ---- MFMA wave tiling: 16 waves = 4 (wm, M) x 4 (wn, N); each wave 16x32 out
    const int wm      = wid & 3, wn = wid >> 2;
    const int lrow    = lane & 15, g4 = lane >> 4;
    const int arow    = (wm << 4) + lrow;          // A row (A-frag: row = lane&15)
    const int drow0   = (wm << 4) + (g4 << 2);     // D rows: drow0 + reg (C/D: m89-verified)
    const int colbase = (wn << 5) + lrow;          // B/D col = lane&15

    // ---- stage 3: h = gelu(feat @ W1 + b1) via 3-term bf16-split MFMA
    {
        floatx4 acc0 = {0,0,0,0}, acc1 = {0,0,0,0};
#pragma unroll
        for (int ks = 0; ks < 4; ++ks) {
            const int k0 = (ks << 5) + (g4 << 3);  // same (lane,reg)->k map for A and B
            float av[8];
            *(float4*)&av[0] = *(const float4*)&s_feat[arow][k0];
            *(float4*)&av[4] = *(const float4*)&s_feat[arow][k0 + 4];
            bfrag8 ahi, alo; split8(av, ahi, alo);
#pragma unroll
            for (int nt = 0; nt < 2; ++nt) {
                const float* wp = W1 + (size_t)k0 * HIDD + colbase + (nt << 4);
                float wv[8];
#pragma unroll
                for (int i = 0; i < 8; ++i) wv[i] = wp[(size_t)i * HIDD];
                bfrag8 bhi, blo; split8(wv, bhi, blo);
                floatx4 a = nt ? acc1 : acc0;
                a = __builtin_amdgcn_mfma_f32_16x16x32_bf16(ahi, bhi, a, 0, 0, 0);
                a = __builtin_amdgcn_mfma_f32_16x16x32_bf16(ahi, blo, a, 0, 0, 0);
                a = __builtin_amdgcn_mfma_f32_16x16x32_bf16(alo, bhi, a, 0, 0, 0);
                if (nt) acc1 = a; else acc0 = a;
            }
        }
#pragma unroll
        for (int nt = 0; nt < 2; ++nt) {
            const int col = colbase + (nt << 4);
            const float bb = b1[col];
            const floatx4 a = nt ? acc1 : acc0;
#pragma unroll
            for (int r = 0; r < 4; ++r)
                s_h[drow0 + r][col] = gelu_exact(a[r] + bb);
        }
    }
    __syncthreads();

    // ---- stage 4: h2 = h @ W2, atom-mean folded into shuffle reduction
    {
        floatx4 acc0 = {0,0,0,0}, acc1 = {0,0,0,0};
#pragma unroll
        for (int ks = 0; ks < 4; ++ks) {
            const int k0 = (ks << 5) + (g4 << 3);
            float av[8];
            *(float4*)&av[0] = *(const float4*)&s_h[arow][k0];
            *(float4*)&av[4] = *(const float4*)&s_h[arow][k0 + 4];
            bfrag8 ahi, alo; split8(av, ahi, alo);
#pragma unroll
            for (int nt = 0; nt < 2; ++nt) {
                const float* wp = W2 + (size_t)k0 * HIDD + colbase + (nt << 4);
                float wv[8];
#pragma unroll
                for (int i = 0; i < 8; ++i) wv[i] = wp[(size_t)i * HIDD];
                bfrag8 bhi, blo; split8(wv, bhi, blo);
                floatx4 a = nt ? acc1 : acc0;
                a = __builtin_amdgcn_mfma_f32_16x16x32_bf16(ahi, bhi, a, 0, 0, 0);
                a = __builtin_amdgcn_mfma_f32_16x16x32_bf16(ahi, blo, a, 0, 0, 0);
                a = __builtin_amdgcn_mfma_f32_16x16x32_bf16(alo, bhi, a, 0, 0, 0);
                if (nt) acc1 = a; else acc0 = a;
            }
        }
        // sum this wave's 16 atom-rows: 4 regs (4 rows) + butterfly over g4 groups
#pragma unroll
        for (int nt = 0; nt < 2; ++nt) {
            const floatx4 a = nt ? acc1 : acc0;
            float s = a[0] + a[1] + a[2] + a[3];
            s += __shfl_xor(s, 16, 64);
            s += __shfl_xor(s, 32, 64);
            if (lane < 16) s_mol[wm][colbase + (nt << 4)] = s;
        }
    }
    __syncthreads();

    // ---- stage 5: mol = mean + b2
    if (tid < HIDD)
        s_molv[tid] = (s_mol[0][tid] + s_mol[1][tid] + s_mol[2][tid] + s_mol[3][tid])
                      * (1.0f / 64.0f) + b2[tid];
    __syncthreads();

    // ---- stage 6: out = mol @ Wo + bo  (K split across thread halves)
    {
        const int col = tid & 511, kh = tid >> 9;
        const float* wop = Wo + (size_t)(kh << 6) * OUTD + col;
        const float* mp  = &s_molv[kh << 6];
        float a = 0.0f;
#pragma unroll 4
        for (int k = 0; k < 64; k += 4) {
            const float4 m4 = *(const float4*)(mp + k);
            a += m4.x * wop[(size_t)(k + 0) * OUTD];
            a += m4.y * wop[(size_t)(k + 1) * OUTD];
            a += m4.z * wop[(size_t)(k + 2) * OUTD];
            a += m4.w * wop[(size_t)(k + 3) * OUTD];
        }
        s_dist[tid] = a;   // s_dist is dead by now; reuse as reduction buffer
    }
    __syncthreads();
    if (tid < OUTD)
        out[(size_t)b * OUTD + tid] = s_dist[tid] + s_dist[tid + 512] + bo[tid];
}
} // namespace

extern "C" void kernel_launch(void* const* d_in, const int* in_sizes, int n_in,
                              void* d_out, int out_size, void* d_ws, size_t ws_size,
                              hipStream_t stream) {
    const int*   atomic_nums = (const int*)  d_in[0];
    const float* coords      = (const float*)d_in[1];
    const float* embed_table = (const float*)d_in[2];
    const float* W1          = (const float*)d_in[3];
    const float* b1          = (const float*)d_in[4];
    const float* W2          = (const float*)d_in[5];
    const float* b2          = (const float*)d_in[6];
    const float* Wo          = (const float*)d_in[7];
    const float* bo          = (const float*)d_in[8];
    const float* centers     = (const float*)d_in[9];
    float*       out         = (float*)d_out;

    mlip_fused<<<NB, 1024, 0, stream>>>(atomic_nums, coords, embed_table,
                                        W1, b1, W2, b2, Wo, bo, centers, out);
}

// Round 3
// 29.413 us; speedup vs baseline: 1.3534x; 1.0658x over previous
//
#include <hip/hip_runtime.h>
#include <math.h>

namespace {
constexpr int NB   = 256;
constexpr int NA   = 64;
constexpr int EMBD = 64;
constexpr int HIDD = 128;
constexpr int OUTD = 512;
constexpr int FP   = 132;   // padded row stride: 4*row mod 32 spreads frag reads to 2-way (free)

typedef __attribute__((ext_vector_type(8))) short bfrag8;   // 8 bf16 = 4 VGPRs
typedef __attribute__((ext_vector_type(4))) float floatx4;  // MFMA accumulator

__device__ __forceinline__ float gelu_exact(float x) {
    return 0.5f * x * (1.0f + erff(x * 0.7071067811865475f));
}

__device__ __forceinline__ unsigned short bf16_rne(float f) {
    unsigned u = __float_as_uint(f);
    u += 0x7fffu + ((u >> 16) & 1u);
    return (unsigned short)(u >> 16);
}

// ---- weight prep: W1,W2 -> bf16 hi/lo in MFMA B-fragment order, once per launch.
// ws layout (shorts): [0)W1hi [16384)W1lo [32768)W2hi [49152)W2lo
// frag idx = ((ks*8+ntile)*64+lane)*8+r  <->  W[ks*32+(lane>>4)*8+r][ntile*16+(lane&15)]
__global__ __launch_bounds__(256, 4)
void prep_weights(const float* __restrict__ W1, const float* __restrict__ W2,
                  short* __restrict__ ws) {
    const int t = blockIdx.x * 256 + threadIdx.x;       // 32768 threads
    const float* W  = (t < 16384) ? W1 : W2;
    const int  base = (t < 16384) ? 0  : 32768;
    const int  idx  = t & 16383;
    const int  r    = idx & 7;
    const int  lane = (idx >> 3) & 63;
    const int  tile = (idx >> 9) & 7;
    const int  ks   = idx >> 12;
    const int  k    = ks * 32 + (lane >> 4) * 8 + r;
    const int  n    = tile * 16 + (lane & 15);
    const float f   = W[k * HIDD + n];
    const unsigned short h = bf16_rne(f);
    const unsigned short l = bf16_rne(f - __uint_as_float((unsigned)h << 16));
    ws[base + idx]         = (short)h;
    ws[base + 16384 + idx] = (short)l;
}

// fast f32 -> (hi,lo) bf16 split: v_cvt_pk_bf16_f32 packs 2 elems/inst
__device__ __forceinline__ void split8(const float* v, bfrag8& hi, bfrag8& lo) {
    union { unsigned u[4]; bfrag8 s; } H, L;
#pragma unroll
    for (int p = 0; p < 4; ++p) {
        const float a = v[2 * p], c = v[2 * p + 1];
        unsigned h;
        asm("v_cvt_pk_bf16_f32 %0, %1, %2" : "=v"(h) : "v"(a), "v"(c));
        const float h0 = __uint_as_float(h << 16);
        const float h1 = __uint_as_float(h & 0xffff0000u);
        unsigned l;
        asm("v_cvt_pk_bf16_f32 %0, %1, %2" : "=v"(l) : "v"(a - h0), "v"(c - h1));
        H.u[p] = h; L.u[p] = l;
    }
    hi = H.s; lo = L.s;
}

__global__ __launch_bounds__(1024, 1)
void mlip_fused(const int*   __restrict__ atomic_nums,
                const float* __restrict__ coords,
                const float* __restrict__ embed_table,
                const float* __restrict__ b1,
                const float* __restrict__ b2,
                const float* __restrict__ Wo, const float* __restrict__ bo,
                const float* __restrict__ centers,
                const short* __restrict__ wfrag,   // prepped W1/W2 hi/lo
                float*       __restrict__ out)
{
    const int b    = blockIdx.x;
    const int tid  = threadIdx.x;
    const int lane = tid & 63;
    const int wid  = tid >> 6;          // 16 waves

    __shared__ float s_dist[NA * NA];   // 16 KB; reused as stage-6 reduction buffer
    __shared__ float s_feat[NA][FP];    // [emb | avg_gauss]
    __shared__ float s_h[NA][FP];       // GEMM1 output
    __shared__ float s_mol[4][HIDD];
    __shared__ float s_molv[HIDD];

    // ---- front section (no internal barriers):
    // per-lane coords of atom `lane`
    const float* cbase = coords + (size_t)b * NA * 3;
    const float cx = cbase[lane * 3 + 0];
    const float cy = cbase[lane * 3 + 1];
    const float cz = cbase[lane * 3 + 2];

    // embedding gather -> s_feat[:,0:64] (z read straight from global, L1-broadcast)
    {
        const int i = tid >> 4, e4 = (tid & 15) << 2;
        const int z = atomic_nums[b * NA + i];
        *(float4*)&s_feat[i][e4] =
            *(const float4*)(embed_table + (size_t)z * EMBD + e4);
    }

    // dist rows this wave will itself consume: i = wid + 16*it  (within-wave dep only)
#pragma unroll
    for (int it = 0; it < 4; ++it) {
        const int i = wid + (it << 4);
        const float xi = __shfl(cx, i, 64);
        const float yi = __shfl(cy, i, 64);
        const float zi = __shfl(cz, i, 64);
        const float dx = xi - cx, dy = yi - cy, dz = zi - cz;
        const float sq = dx * dx + dy * dy + dz * dz;
        s_dist[(i << 6) + lane] = sq > 0.0f ? sqrtf(sq) : 0.0f;
    }

    // gaussian smear, mean over j -> s_feat[:,64:128]
    {
        const float K2  = -2.8853900817779268f;   // -2*log2(e)
        const float c   = centers[lane];
        const float nu2 = -2.0f * K2 * c;
        const float vc  = K2 * c * c;
#pragma unroll
        for (int it = 0; it < 4; ++it) {
            const int i = wid + (it << 4);
            const float* drow = &s_dist[i << 6];  // rows written by THIS wave
            float acc = 0.0f;
#pragma unroll
            for (int j4 = 0; j4 < NA; j4 += 4) {
                const float4 d4 = *(const float4*)(drow + j4);
                acc += __builtin_amdgcn_exp2f(fmaf(d4.x, fmaf(K2, d4.x, nu2), vc));
                acc += __builtin_amdgcn_exp2f(fmaf(d4.y, fmaf(K2, d4.y, nu2), vc));
                acc += __builtin_amdgcn_exp2f(fmaf(d4.z, fmaf(K2, d4.z, nu2), vc));
                acc += __builtin_amdgcn_exp2f(fmaf(d4.w, fmaf(K2, d4.w, nu2), vc));
            }
            s_feat[i][EMBD + lane] = acc * (1.0f / 64.0f);
        }
    }
    __syncthreads();                                   // barrier 1

    // ---- MFMA tiling: 16 waves = 4 wm x 4 wn, each wave 16x32 of the 64x128 output
    const int wm      = wid & 3, wn = wid >> 2;
    const int lrow    = lane & 15, g4 = lane >> 4;
    const int arow    = (wm << 4) + lrow;
    const int drow0   = (wm << 4) + (g4 << 2);
    const int colbase = (wn << 5) + lrow;

    const short* w1hi = wfrag;
    const short* w1lo = wfrag + 16384;
    const short* w2hi = wfrag + 32768;
    const short* w2lo = wfrag + 49152;

    // ---- stage 3: h = gelu(feat @ W1 + b1)
    {
        floatx4 acc0 = {0,0,0,0}, acc1 = {0,0,0,0};
#pragma unroll
        for (int ks = 0; ks < 4; ++ks) {
            const int k0 = (ks << 5) + (g4 << 3);
            float av[8];
            *(float4*)&av[0] = *(const float4*)&s_feat[arow][k0];
            *(float4*)&av[4] = *(const float4*)&s_feat[arow][k0 + 4];
            bfrag8 ahi, alo; split8(av, ahi, alo);
#pragma unroll
            for (int nt = 0; nt < 2; ++nt) {
                const int fidx = (((ks << 3) + (wn << 1) + nt) << 6) + lane;
                const bfrag8 bhi = *(const bfrag8*)&w1hi[fidx << 3];
                const bfrag8 blo = *(const bfrag8*)&w1lo[fidx << 3];
                floatx4 a = nt ? acc1 : acc0;
                a = __builtin_amdgcn_mfma_f32_16x16x32_bf16(ahi, bhi, a, 0, 0, 0);
                a = __builtin_amdgcn_mfma_f32_16x16x32_bf16(ahi, blo, a, 0, 0, 0);
                a = __builtin_amdgcn_mfma_f32_16x16x32_bf16(alo, bhi, a, 0, 0, 0);
                if (nt) acc1 = a; else acc0 = a;
            }
        }
#pragma unroll
        for (int nt = 0; nt < 2; ++nt) {
            const int col = colbase + (nt << 4);
            const float bb = b1[col];
            const floatx4 a = nt ? acc1 : acc0;
#pragma unroll
            for (int r = 0; r < 4; ++r)
                s_h[drow0 + r][col] = gelu_exact(a[r] + bb);
        }
    }
    __syncthreads();                                   // barrier 2

    // ---- stage 4: h2 = h @ W2, atom-sum folded into shuffle reduction
    {
        floatx4 acc0 = {0,0,0,0}, acc1 = {0,0,0,0};
#pragma unroll
        for (int ks = 0; ks < 4; ++ks) {
            const int k0 = (ks << 5) + (g4 << 3);
            float av[8];
            *(float4*)&av[0] = *(const float4*)&s_h[arow][k0];
            *(float4*)&av[4] = *(const float4*)&s_h[arow][k0 + 4];
            bfrag8 ahi, alo; split8(av, ahi, alo);
#pragma unroll
            for (int nt = 0; nt < 2; ++nt) {
                const int fidx = (((ks << 3) + (wn << 1) + nt) << 6) + lane;
                const bfrag8 bhi = *(const bfrag8*)&w2hi[fidx << 3];
                const bfrag8 blo = *(const bfrag8*)&w2lo[fidx << 3];
                floatx4 a = nt ? acc1 : acc0;
                a = __builtin_amdgcn_mfma_f32_16x16x32_bf16(ahi, bhi, a, 0, 0, 0);
                a = __builtin_amdgcn_mfma_f32_16x16x32_bf16(ahi, blo, a, 0, 0, 0);
                a = __builtin_amdgcn_mfma_f32_16x16x32_bf16(alo, bhi, a, 0, 0, 0);
                if (nt) acc1 = a; else acc0 = a;
            }
        }
#pragma unroll
        for (int nt = 0; nt < 2; ++nt) {
            const floatx4 a = nt ? acc1 : acc0;
            float s = a[0] + a[1] + a[2] + a[3];
            s += __shfl_xor(s, 16, 64);
            s += __shfl_xor(s, 32, 64);
            if (lane < 16) s_mol[wm][colbase + (nt << 4)] = s;
        }
    }
    __syncthreads();                                   // barrier 3

    // ---- stage 5: mol = mean + b2
    if (tid < HIDD)
        s_molv[tid] = (s_mol[0][tid] + s_mol[1][tid] + s_mol[2][tid] + s_mol[3][tid])
                      * (1.0f / 64.0f) + b2[tid];
    __syncthreads();                                   // barrier 4

    // ---- stage 6: out = mol @ Wo + bo  (K split across thread halves)
    {
        const int col = tid & 511, kh = tid >> 9;
        const float* wop = Wo + (size_t)(kh << 6) * OUTD + col;
        const float* mp  = &s_molv[kh << 6];
        float a = 0.0f;
#pragma unroll 4
        for (int k = 0; k < 64; k += 4) {
            const float4 m4 = *(const float4*)(mp + k);
            a += m4.x * wop[(size_t)(k + 0) * OUTD];
            a += m4.y * wop[(size_t)(k + 1) * OUTD];
            a += m4.z * wop[(size_t)(k + 2) * OUTD];
            a += m4.w * wop[(size_t)(k + 3) * OUTD];
        }
        s_dist[tid] = a;     // s_dist dead; reuse as reduction buffer
    }
    __syncthreads();                                   // barrier 5
    if (tid < OUTD)
        out[(size_t)b * OUTD + tid] = s_dist[tid] + s_dist[tid + 512] + bo[tid];
}
} // namespace

extern "C" void kernel_launch(void* const* d_in, const int* in_sizes, int n_in,
                              void* d_out, int out_size, void* d_ws, size_t ws_size,
                              hipStream_t stream) {
    const int*   atomic_nums = (const int*)  d_in[0];
    const float* coords      = (const float*)d_in[1];
    const float* embed_table = (const float*)d_in[2];
    const float* W1          = (const float*)d_in[3];
    const float* b1          = (const float*)d_in[4];
    const float* W2          = (const float*)d_in[5];
    const float* b2          = (const float*)d_in[6];
    const float* Wo          = (const float*)d_in[7];
    const float* bo          = (const float*)d_in[8];
    const float* centers     = (const float*)d_in[9];
    float*       out         = (float*)d_out;
    short*       ws          = (short*)d_ws;   // needs 128 KB

    prep_weights<<<128, 256, 0, stream>>>(W1, W2, ws);
    mlip_fused<<<NB, 1024, 0, stream>>>(atomic_nums, coords, embed_table,
                                        b1, b2, Wo, bo, centers, ws, out);
}